// Round 1
// baseline (66.157 us; speedup 1.0000x reference)
//
#include <hip/hip_runtime.h>
#include <hip/hip_bf16.h>

// Problem geometry (fixed by reference): uvs [B=16, J=16, M=512, D=256] fp32.
// J = 2K; j<8 is "u" half, j>=8 is "v" half. Partner slice jp = j^8... (j+8 / j-8).
// Gate for row m of slice (b,j): sign(dot(row, colsum(partner slice))) > 0.

#define B_ 16
#define J_ 16
#define M_ 512
#define D_ 256
#define D4_ 64          // D/4 float4s per row
#define S_ 4            // m-splits in colsum kernel

// ---------------------------------------------------------------------------
// Kernel 1: partial column sums. Grid = B*J*S = 1024 blocks, 256 threads.
// Block (bj, s) sums rows [s*128, s*128+128) of slice bj into part[bj][s][D].
// Thread t: lane l = t&63 owns float4 column l; wave w = t>>6 strides rows by 4.
// ---------------------------------------------------------------------------
__global__ __launch_bounds__(256) void k_colsum(const float4* __restrict__ in,
                                                float4* __restrict__ part) {
    const int blk = blockIdx.x;
    const int s  = blk & (S_ - 1);
    const int bj = blk >> 2;            // b*J + j, in [0, 256)
    const int t  = threadIdx.x;
    const int l  = t & 63;
    const int w  = t >> 6;

    const float4* base = in + (size_t)bj * (M_ * D4_) + (size_t)(s * 128 + w) * D4_ + l;

    float4 acc = make_float4(0.f, 0.f, 0.f, 0.f);
#pragma unroll 8
    for (int i = 0; i < 32; ++i) {
        float4 v = base[(size_t)(4 * i) * D4_];
        acc.x += v.x; acc.y += v.y; acc.z += v.z; acc.w += v.w;
    }

    __shared__ float4 red[256];
    red[t] = acc;
    __syncthreads();
    if (t < 64) {
        float4 a = red[t], b = red[t + 64], c = red[t + 128], d = red[t + 192];
        float4 r;
        r.x = (a.x + b.x) + (c.x + d.x);
        r.y = (a.y + b.y) + (c.y + d.y);
        r.z = (a.z + b.z) + (c.z + d.z);
        r.w = (a.w + b.w) + (c.w + d.w);
        part[(size_t)(bj * S_ + s) * D4_ + t] = r;
    }
}

// ---------------------------------------------------------------------------
// Kernel 2: gate + write. Grid = B*J*(M/64) = 2048 blocks, 256 threads.
// Block handles 64 rows of slice (b,j); each of 4 waves does 16 rows.
// Lane l keeps the partner-sum float4 for columns [4l,4l+3] in registers.
// Per row: coalesced float4 load -> lane dot -> 6-step shfl_xor reduce ->
// gate = (dot > 0) -> gated float4 store. relu(sign(x)) == (x>0 ? 1 : 0).
// ---------------------------------------------------------------------------
__global__ __launch_bounds__(256) void k_gate(const float4* __restrict__ in,
                                              const float4* __restrict__ part,
                                              float4* __restrict__ out) {
    const int blk   = blockIdx.x;
    const int chunk = blk & 7;          // which 64-row chunk
    const int bj    = blk >> 3;
    const int b     = bj >> 4;
    const int j     = bj & 15;
    const int jp    = (j < 8) ? (j + 8) : (j - 8);
    const int t     = threadIdx.x;
    const int l     = t & 63;
    const int w     = t >> 6;

    // Sum the 4 m-split partials of the partner slice -> per-lane sum vector.
    const int pbase = (b * J_ + jp) * (S_ * D4_) + l;
    float4 s0 = part[pbase], s1 = part[pbase + 64],
           s2 = part[pbase + 128], s3 = part[pbase + 192];
    float4 sv;
    sv.x = (s0.x + s1.x) + (s2.x + s3.x);
    sv.y = (s0.y + s1.y) + (s2.y + s3.y);
    sv.z = (s0.z + s1.z) + (s2.z + s3.z);
    sv.w = (s0.w + s1.w) + (s2.w + s3.w);

    const size_t rowbase = (size_t)bj * (M_ * D4_) + (size_t)(chunk * 64 + w * 16) * D4_ + l;
    const float4* inb = in + rowbase;
    float4* outb = out + rowbase;

#pragma unroll 4
    for (int r = 0; r < 16; ++r) {
        float4 v = inb[(size_t)r * D4_];
        float p = v.x * sv.x + v.y * sv.y + v.z * sv.z + v.w * sv.w;
#pragma unroll
        for (int off = 32; off; off >>= 1) p += __shfl_xor(p, off, 64);
        float g = (p > 0.f) ? 1.f : 0.f;
        float4 o;
        o.x = v.x * g; o.y = v.y * g; o.z = v.z * g; o.w = v.w * g;
        outb[(size_t)r * D4_] = o;
    }
}

extern "C" void kernel_launch(void* const* d_in, const int* in_sizes, int n_in,
                              void* d_out, int out_size, void* d_ws, size_t ws_size,
                              hipStream_t stream) {
    const float4* in  = (const float4*)d_in[0];
    float4*       out = (float4*)d_out;
    float4*       part = (float4*)d_ws;   // B*J*S*D floats = 1 MiB; fully written before read

    k_colsum<<<B_ * J_ * S_, 256, 0, stream>>>(in, part);
    k_gate<<<B_ * J_ * (M_ / 64), 256, 0, stream>>>(in, part, out);
}

// Round 2
// 65.746 us; speedup vs baseline: 1.0062x; 1.0062x over previous
//
#include <hip/hip_runtime.h>
#include <hip/hip_bf16.h>

// Problem geometry (fixed by reference): uvs [B=16, J=16, M=512, D=256] fp32.
// J = 2K; j<8 is "u" half, j>=8 is "v" half. Partner slice jp = j^8 (j+8 / j-8).
// Gate for row m of slice (b,j): sign(dot(row, colsum(partner slice))) > 0.
//
// Structure: K1 = partial column sums (read 128 MiB), K2 = gate+write
// (read 128 MiB + write 128 MiB). R1 showed K2's re-read missed L3 because the
// 128 MiB output write-allocated into the 256 MiB Infinity Cache and evicted
// the input. Fix: NON-TEMPORAL output stores -> input stays L3-resident,
// K2 reads served from L3, HBM traffic/replay ~= the write stream only.

#define B_ 16
#define J_ 16
#define M_ 512
#define D_ 256
#define D4_ 64          // D/4 float4s per row
#define S_ 4            // m-splits in colsum kernel

typedef float f32x4 __attribute__((ext_vector_type(4)));

// ---------------------------------------------------------------------------
// Kernel 1: partial column sums. Grid = B*J*S = 1024 blocks, 256 threads.
// Block (bj, s) sums rows [s*128, s*128+128) of slice bj into part[bj][s][D].
// Thread t: lane l = t&63 owns float4 column l; wave w = t>>6 strides rows by 4.
// ---------------------------------------------------------------------------
__global__ __launch_bounds__(256) void k_colsum(const float4* __restrict__ in,
                                                float4* __restrict__ part) {
    const int blk = blockIdx.x;
    const int s  = blk & (S_ - 1);
    const int bj = blk >> 2;            // b*J + j, in [0, 256)
    const int t  = threadIdx.x;
    const int l  = t & 63;
    const int w  = t >> 6;

    const float4* base = in + (size_t)bj * (M_ * D4_) + (size_t)(s * 128 + w) * D4_ + l;

    float4 acc = make_float4(0.f, 0.f, 0.f, 0.f);
#pragma unroll 8
    for (int i = 0; i < 32; ++i) {
        float4 v = base[(size_t)(4 * i) * D4_];
        acc.x += v.x; acc.y += v.y; acc.z += v.z; acc.w += v.w;
    }

    __shared__ float4 red[256];
    red[t] = acc;
    __syncthreads();
    if (t < 64) {
        float4 a = red[t], b = red[t + 64], c = red[t + 128], d = red[t + 192];
        float4 r;
        r.x = (a.x + b.x) + (c.x + d.x);
        r.y = (a.y + b.y) + (c.y + d.y);
        r.z = (a.z + b.z) + (c.z + d.z);
        r.w = (a.w + b.w) + (c.w + d.w);
        part[(size_t)(bj * S_ + s) * D4_ + t] = r;
    }
}

// ---------------------------------------------------------------------------
// Kernel 2: gate + write. Grid = B*J*(M/64) = 2048 blocks, 256 threads.
// Block handles 64 rows of slice (b,j); each of 4 waves does 16 rows.
// Lane l keeps the partner-sum float4 for columns [4l,4l+3] in registers.
// Per row: float4 load (L3-hit) -> lane dot -> 6-step shfl_xor reduce ->
// gate = (dot > 0) -> gated NON-TEMPORAL float4 store (don't pollute L3).
// relu(sign(x)) == (x>0 ? 1 : 0).
// ---------------------------------------------------------------------------
__global__ __launch_bounds__(256) void k_gate(const float4* __restrict__ in,
                                              const float4* __restrict__ part,
                                              float4* __restrict__ out) {
    const int blk   = blockIdx.x;
    const int chunk = blk & 7;          // which 64-row chunk
    const int bj    = blk >> 3;
    const int b     = bj >> 4;
    const int j     = bj & 15;
    const int jp    = (j < 8) ? (j + 8) : (j - 8);
    const int t     = threadIdx.x;
    const int l     = t & 63;
    const int w     = t >> 6;

    // Sum the 4 m-split partials of the partner slice -> per-lane sum vector.
    const int pbase = (b * J_ + jp) * (S_ * D4_) + l;
    float4 s0 = part[pbase], s1 = part[pbase + 64],
           s2 = part[pbase + 128], s3 = part[pbase + 192];
    float4 sv;
    sv.x = (s0.x + s1.x) + (s2.x + s3.x);
    sv.y = (s0.y + s1.y) + (s2.y + s3.y);
    sv.z = (s0.z + s1.z) + (s2.z + s3.z);
    sv.w = (s0.w + s1.w) + (s2.w + s3.w);

    const size_t rowbase = (size_t)bj * (M_ * D4_) + (size_t)(chunk * 64 + w * 16) * D4_ + l;
    const float4* inb = in + rowbase;
    f32x4* outb = (f32x4*)(out + rowbase);

#pragma unroll 4
    for (int r = 0; r < 16; ++r) {
        float4 v = inb[(size_t)r * D4_];
        float p = v.x * sv.x + v.y * sv.y + v.z * sv.z + v.w * sv.w;
#pragma unroll
        for (int off = 32; off; off >>= 1) p += __shfl_xor(p, off, 64);
        float g = (p > 0.f) ? 1.f : 0.f;
        f32x4 o;
        o.x = v.x * g; o.y = v.y * g; o.z = v.z * g; o.w = v.w * g;
        __builtin_nontemporal_store(o, outb + (size_t)r * D4_);
    }
}

extern "C" void kernel_launch(void* const* d_in, const int* in_sizes, int n_in,
                              void* d_out, int out_size, void* d_ws, size_t ws_size,
                              hipStream_t stream) {
    const float4* in  = (const float4*)d_in[0];
    float4*       out = (float4*)d_out;
    float4*       part = (float4*)d_ws;   // B*J*S*D floats = 1 MiB; fully written before read

    k_colsum<<<B_ * J_ * S_, 256, 0, stream>>>(in, part);
    k_gate<<<B_ * J_ * (M_ / 64), 256, 0, stream>>>(in, part, out);
}

// Round 3
// 64.131 us; speedup vs baseline: 1.0316x; 1.0252x over previous
//
#include <hip/hip_runtime.h>
#include <hip/hip_bf16.h>

// uvs [B=16, J=16, M=512, D=256] fp32. j<8 = u (k=j), j>=8 = v (k=j-8).
// gate_u[b,k,m] = (dot(u[b,k,m,:], colsum(v[b,k])) > 0)
// gate_v[b,k,n] = (dot(v[b,k,n,:], colsum(u[b,k])) > 0)
//
// 3-phase structure minimizing HBM reads (u read ONCE, v read twice with the
// re-read aimed at L3):
//   K1: v -> vsum partials                       (read 64 MiB)
//   K2: u -> gated-u write + usum partials       (NT read 64, NT write 64)
//   K3: v re-read -> gated-v write               (read 64 [L3?], NT write 64)
// Deterministic tree reductions through d_ws partials; no atomics (gate signs
// must be replay-stable).

#define B_  16
#define J_  16
#define K_  8
#define M_  512
#define D4_ 64          // 256 floats = 64 float4 per row
#define S_  8           // m-splits per slice -> 128*8 = 1024 blocks per pass

typedef float f32x4 __attribute__((ext_vector_type(4)));

// --------------------------------------------------------------------------
// K1: partial column sums of the v half.
// Grid 1024 = (b,k) x s. Block sums rows [s*64, s*64+64) of v[b,k].
// Lane l owns float4 column l; wave w handles 16 rows.
// --------------------------------------------------------------------------
__global__ __launch_bounds__(256) void k_vsum(const float4* __restrict__ in,
                                              float4* __restrict__ vpart) {
    const int blk = blockIdx.x;
    const int s   = blk & (S_ - 1);
    const int bk  = blk >> 3;                 // [0,128)
    const int b   = bk >> 3, k = bk & 7;
    const int t   = threadIdx.x;
    const int l   = t & 63;
    const int w   = t >> 6;

    const float4* base = in + ((size_t)(b * J_ + 8 + k) * M_ + s * 64 + w * 16) * D4_ + l;

    float4 acc = make_float4(0.f, 0.f, 0.f, 0.f);
#pragma unroll
    for (int i = 0; i < 16; ++i) {
        float4 v = base[(size_t)i * D4_];
        acc.x += v.x; acc.y += v.y; acc.z += v.z; acc.w += v.w;
    }

    __shared__ float4 red[256];
    red[t] = acc;
    __syncthreads();
    if (t < 64) {
        float4 a = red[t], c = red[t + 64], d = red[t + 128], e = red[t + 192];
        float4 r;
        r.x = (a.x + c.x) + (d.x + e.x);
        r.y = (a.y + c.y) + (d.y + e.y);
        r.z = (a.z + c.z) + (d.z + e.z);
        r.w = (a.w + c.w) + (d.w + e.w);
        vpart[(size_t)(bk * S_ + s) * 64 + t] = r;
    }
}

// --------------------------------------------------------------------------
// K2: u pass. Reduce vsum partials -> registers; stream 64 u rows:
// NT load -> dot -> shfl_xor reduce -> gate -> NT store gated u.
// Simultaneously accumulate this block's partial usum -> upart.
// --------------------------------------------------------------------------
__global__ __launch_bounds__(256) void k_upass(const float4* __restrict__ in,
                                               const float4* __restrict__ vpart,
                                               float4* __restrict__ upart,
                                               float4* __restrict__ out) {
    const int blk = blockIdx.x;
    const int s   = blk & (S_ - 1);
    const int bk  = blk >> 3;
    const int b   = bk >> 3, k = bk & 7;
    const int t   = threadIdx.x;
    const int l   = t & 63;
    const int w   = t >> 6;

    // vsum for this (b,k): sum the 8 partials (deterministic order).
    float4 sv = make_float4(0.f, 0.f, 0.f, 0.f);
#pragma unroll
    for (int q = 0; q < S_; ++q) {
        float4 p = vpart[(size_t)(bk * S_ + q) * 64 + l];
        sv.x += p.x; sv.y += p.y; sv.z += p.z; sv.w += p.w;
    }

    const size_t rowbase = ((size_t)(b * J_ + k) * M_ + s * 64 + w * 16) * D4_ + l;
    const f32x4* inb  = (const f32x4*)(in + rowbase);
    f32x4*       outb = (f32x4*)(out + rowbase);

    float4 acc = make_float4(0.f, 0.f, 0.f, 0.f);   // partial usum
#pragma unroll 4
    for (int r = 0; r < 16; ++r) {
        f32x4 v = __builtin_nontemporal_load(inb + (size_t)r * D4_);
        acc.x += v.x; acc.y += v.y; acc.z += v.z; acc.w += v.w;  // ungated colsum
        float p = v.x * sv.x + v.y * sv.y + v.z * sv.z + v.w * sv.w;
#pragma unroll
        for (int off = 32; off; off >>= 1) p += __shfl_xor(p, off, 64);
        float g = (p > 0.f) ? 1.f : 0.f;
        f32x4 o; o.x = v.x * g; o.y = v.y * g; o.z = v.z * g; o.w = v.w * g;
        __builtin_nontemporal_store(o, outb + (size_t)r * D4_);
    }

    __shared__ float4 red[256];
    red[t] = acc;
    __syncthreads();
    if (t < 64) {
        float4 a = red[t], c = red[t + 64], d = red[t + 128], e = red[t + 192];
        float4 r;
        r.x = (a.x + c.x) + (d.x + e.x);
        r.y = (a.y + c.y) + (d.y + e.y);
        r.z = (a.z + c.z) + (d.z + e.z);
        r.w = (a.w + c.w) + (d.w + e.w);
        upart[(size_t)(bk * S_ + s) * 64 + t] = r;
    }
}

// --------------------------------------------------------------------------
// K3: v pass. Reduce usum partials -> registers; re-read v (L3-resident
// hopefully), gate, NT store gated v.
// --------------------------------------------------------------------------
__global__ __launch_bounds__(256) void k_vpass(const float4* __restrict__ in,
                                               const float4* __restrict__ upart,
                                               float4* __restrict__ out) {
    const int blk = blockIdx.x;
    const int s   = blk & (S_ - 1);
    const int bk  = blk >> 3;
    const int b   = bk >> 3, k = bk & 7;
    const int t   = threadIdx.x;
    const int l   = t & 63;
    const int w   = t >> 6;

    float4 su = make_float4(0.f, 0.f, 0.f, 0.f);
#pragma unroll
    for (int q = 0; q < S_; ++q) {
        float4 p = upart[(size_t)(bk * S_ + q) * 64 + l];
        su.x += p.x; su.y += p.y; su.z += p.z; su.w += p.w;
    }

    const size_t rowbase = ((size_t)(b * J_ + 8 + k) * M_ + s * 64 + w * 16) * D4_ + l;
    const float4* inb  = in + rowbase;
    f32x4*        outb = (f32x4*)(out + rowbase);

#pragma unroll 4
    for (int r = 0; r < 16; ++r) {
        float4 v = inb[(size_t)r * D4_];          // allocating load: want L3 hit
        float p = v.x * su.x + v.y * su.y + v.z * su.z + v.w * su.w;
#pragma unroll
        for (int off = 32; off; off >>= 1) p += __shfl_xor(p, off, 64);
        float g = (p > 0.f) ? 1.f : 0.f;
        f32x4 o; o.x = v.x * g; o.y = v.y * g; o.z = v.z * g; o.w = v.w * g;
        __builtin_nontemporal_store(o, outb + (size_t)r * D4_);
    }
}

extern "C" void kernel_launch(void* const* d_in, const int* in_sizes, int n_in,
                              void* d_out, int out_size, void* d_ws, size_t ws_size,
                              hipStream_t stream) {
    const float4* in  = (const float4*)d_in[0];
    float4*       out = (float4*)d_out;
    // Workspace: vpart 1 MiB @ 0, upart 1 MiB @ 1 MiB. Fully written before read.
    float4* vpart = (float4*)d_ws;
    float4* upart = (float4*)((char*)d_ws + (1u << 20));

    const int grid = B_ * K_ * S_;   // 1024
    k_vsum <<<grid, 256, 0, stream>>>(in, vpart);
    k_upass<<<grid, 256, 0, stream>>>(in, vpart, upart, out);
    k_vpass<<<grid, 256, 0, stream>>>(in, upart, out);
}